// Round 1
// baseline (1504.444 us; speedup 1.0000x reference)
//
#include <hip/hip_runtime.h>
#include <hip/hip_bf16.h>
#include <stdint.h>

#define N_NODES 100000
#define N_EDGES 1000000
#define D_FEAT  64
#define QMAX    127.0f

// ws layout:
//   [0..16)   Scalars {layout_flag, amax_msg, amax1, amax2}  (uint bits of nonneg floats)
//   [256 ..)  float r[N_NODES]  per-node rowmax of |x|
struct Scalars {
    unsigned int layout_flag;  // bit1: mask stored as f32, bit0: as bytes, none: as int32
    unsigned int amax_msg;
    unsigned int amax1;
    unsigned int amax2;
};

__device__ __forceinline__ bool get_mask(const void* mp, unsigned int flag, int i) {
    if (flag & 2u) return ((const float*)mp)[i] != 0.0f;
    if (flag & 1u) return ((const unsigned char*)mp)[i] != 0;
    return ((const int*)mp)[i] != 0;
}

__device__ __forceinline__ float wave_max(float v) {
    #pragma unroll
    for (int o = 32; o > 0; o >>= 1) v = fmaxf(v, __shfl_xor(v, o, 64));
    return v;
}

__device__ __forceinline__ float dq(float x, float scale) {
    float t = rintf(x / scale);                 // round half-to-even, matches jnp.round
    t = fminf(fmaxf(t, -QMAX - 1.0f), QMAX);    // clip to [-128, 127]
    return t * scale;
}

// Detect how the bool mask was uploaded: int32 words are only 0/1; byte-packed
// bools produce words with upper bytes set; f32 produces 0x3F800000 words.
__global__ void detect_kernel(const unsigned int* mw, Scalars* sc) {
    unsigned int f = 0;
    for (int i = blockIdx.x * blockDim.x + threadIdx.x; i < N_NODES / 4;
         i += gridDim.x * blockDim.x) {
        unsigned int w = mw[i];
        if (w == 0x3F800000u) f |= 2u;
        else if (w & 0xFFFFFF00u) f |= 1u;
    }
    if (f) atomicOr(&sc->layout_flag, f);
}

// r[i] = max_j |x[i,j]|   (one 64-lane wave per row)
__global__ void rowmax_kernel(const float* __restrict__ x, float* __restrict__ r) {
    int gtid = blockIdx.x * blockDim.x + threadIdx.x;
    int row = gtid >> 6, lane = gtid & 63;
    if (row >= N_NODES) return;
    float v = fabsf(x[row * D_FEAT + lane]);
    v = wave_max(v);
    if (lane == 0) r[row] = v;
}

// amax_msg = max over edges with unprotected src of r[src]
__global__ void amax_msg_kernel(const int* __restrict__ src, const void* mask,
                                const float* __restrict__ r, Scalars* sc) {
    unsigned int flag = sc->layout_flag;
    float v = 0.0f;
    for (int e = blockIdx.x * blockDim.x + threadIdx.x; e < N_EDGES;
         e += gridDim.x * blockDim.x) {
        int s = src[e];
        if (!get_mask(mask, flag, s)) v = fmaxf(v, r[s]);
    }
    v = wave_max(v);
    if ((threadIdx.x & 63) == 0 && v > 0.0f)
        atomicMax(&sc->amax_msg, __float_as_uint(v));
}

// Fused message-quant + segment_sum: one wave per edge, lane = feature.
__global__ void scatter_kernel(const float* __restrict__ x, const int* __restrict__ src,
                               const int* __restrict__ dst, const void* mask,
                               const Scalars* __restrict__ sc, float* __restrict__ aggr) {
    int gtid = blockIdx.x * blockDim.x + threadIdx.x;
    int e = gtid >> 6, lane = gtid & 63;
    if (e >= N_EDGES) return;
    unsigned int flag = sc->layout_flag;
    float scale = fmaxf(__uint_as_float(sc->amax_msg) / QMAX, 1e-8f);
    int s = src[e], d = dst[e];
    float v = x[s * D_FEAT + lane];
    if (!get_mask(mask, flag, s)) v = dq(v, scale);
    atomicAdd(&aggr[d * D_FEAT + lane], v);
}

// STAGE 1: amax1 = max |aggr| over unprotected rows
// STAGE 2: amax2 = max |dq(aggr, s1)| over unprotected rows
template <int STAGE>
__global__ void amax_aggr_kernel(const float* __restrict__ aggr, const void* mask,
                                 Scalars* sc) {
    int gtid = blockIdx.x * blockDim.x + threadIdx.x;
    int row = gtid >> 6, lane = gtid & 63;
    if (row >= N_NODES) return;
    unsigned int flag = sc->layout_flag;
    float v = 0.0f;
    if (!get_mask(mask, flag, row)) {
        float a = aggr[row * D_FEAT + lane];
        if (STAGE == 2) {
            float s1 = fmaxf(__uint_as_float(sc->amax1) / QMAX, 1e-8f);
            a = dq(a, s1);
        }
        v = fabsf(a);
    }
    v = wave_max(v);
    if (lane == 0 && v > 0.0f)
        atomicMax(STAGE == 1 ? &sc->amax1 : &sc->amax2, __float_as_uint(v));
}

// out = protected ? aggr : dq(dq(aggr, s1), s2)   (in place over d_out)
__global__ void final_kernel(float* __restrict__ aggr, const void* mask,
                             const Scalars* __restrict__ sc) {
    int gtid = blockIdx.x * blockDim.x + threadIdx.x;
    if (gtid >= N_NODES * D_FEAT) return;
    int row = gtid >> 6;
    unsigned int flag = sc->layout_flag;
    if (get_mask(mask, flag, row)) return;  // identity for protected rows
    float s1 = fmaxf(__uint_as_float(sc->amax1) / QMAX, 1e-8f);
    float s2 = fmaxf(__uint_as_float(sc->amax2) / QMAX, 1e-8f);
    float a = aggr[gtid];
    a = dq(a, s1);
    a = dq(a, s2);
    aggr[gtid] = a;
}

extern "C" void kernel_launch(void* const* d_in, const int* in_sizes, int n_in,
                              void* d_out, int out_size, void* d_ws, size_t ws_size,
                              hipStream_t stream) {
    const float* x   = (const float*)d_in[0];
    const int*   ei  = (const int*)d_in[1];
    const void*  mask = d_in[2];
    const int* src = ei;
    const int* dst = ei + N_EDGES;
    float* out = (float*)d_out;

    Scalars* sc = (Scalars*)d_ws;
    float* r = (float*)((char*)d_ws + 256);

    hipMemsetAsync(d_ws, 0, 256, stream);
    hipMemsetAsync(d_out, 0, (size_t)out_size * sizeof(float), stream);

    detect_kernel<<<98, 256, 0, stream>>>((const unsigned int*)mask, sc);

    const int ROW_THREADS = N_NODES * D_FEAT;           // 6.4M, /256 exact
    rowmax_kernel<<<ROW_THREADS / 256, 256, 0, stream>>>(x, r);

    amax_msg_kernel<<<2048, 256, 0, stream>>>(src, mask, r, sc);

    const long long SC_THREADS = (long long)N_EDGES * D_FEAT;  // 64M
    scatter_kernel<<<(int)(SC_THREADS / 256), 256, 0, stream>>>(x, src, dst, mask, sc, out);

    amax_aggr_kernel<1><<<ROW_THREADS / 256, 256, 0, stream>>>(out, mask, sc);
    amax_aggr_kernel<2><<<ROW_THREADS / 256, 256, 0, stream>>>(out, mask, sc);
    final_kernel<<<ROW_THREADS / 256, 256, 0, stream>>>(out, mask, sc);
}

// Round 2
// 909.729 us; speedup vs baseline: 1.6537x; 1.6537x over previous
//
#include <hip/hip_runtime.h>
#include <hip/hip_bf16.h>
#include <stdint.h>

#define N_NODES 100000
#define N_EDGES 1000000
#define D_FEAT  64
#define QMAX    127.0f

// ws layout:
//   [0..16)   Scalars {layout_flag, amax_msg, amax1, pad}  (uint bits of nonneg floats)
//   [256 ..)  float r[N_NODES]  per-node rowmax of |x|
struct Scalars {
    unsigned int layout_flag;  // bit1: mask stored as f32, bit0: as bytes, none: as int32
    unsigned int amax_msg;
    unsigned int amax1;
    unsigned int pad;
};

__device__ __forceinline__ bool get_mask(const void* mp, unsigned int flag, int i) {
    if (flag & 2u) return ((const float*)mp)[i] != 0.0f;
    if (flag & 1u) return ((const unsigned char*)mp)[i] != 0;
    return ((const int*)mp)[i] != 0;
}

__device__ __forceinline__ float wave_max(float v) {
    #pragma unroll
    for (int o = 32; o > 0; o >>= 1) v = fmaxf(v, __shfl_xor(v, o, 64));
    return v;
}

// block-level max (256 threads = 4 waves), then ONE global atomic per block.
__device__ __forceinline__ void block_atomic_max(float v, unsigned int* target) {
    __shared__ float sm[4];
    v = wave_max(v);
    if ((threadIdx.x & 63) == 0) sm[threadIdx.x >> 6] = v;
    __syncthreads();
    if (threadIdx.x == 0) {
        v = fmaxf(fmaxf(sm[0], sm[1]), fmaxf(sm[2], sm[3]));
        if (v > 0.0f) atomicMax(target, __float_as_uint(v));
    }
}

__device__ __forceinline__ float dq(float x, float scale) {
    float t = rintf(x / scale);                 // round half-to-even, matches jnp.round
    t = fminf(fmaxf(t, -QMAX - 1.0f), QMAX);    // clip to [-128, 127]
    return t * scale;
}

// Detect how the bool mask was uploaded (int32 / bytes / f32 words).
__global__ void detect_kernel(const unsigned int* mw, Scalars* sc) {
    unsigned int f = 0;
    for (int i = blockIdx.x * blockDim.x + threadIdx.x; i < N_NODES / 4;
         i += gridDim.x * blockDim.x) {
        unsigned int w = mw[i];
        if (w == 0x3F800000u) f |= 2u;
        else if (w & 0xFFFFFF00u) f |= 1u;
    }
    if (f) atomicOr(&sc->layout_flag, f);
}

// r[row] = max_j |x[row,j]|  — 16 lanes per row, float4 loads.
__global__ void rowmax_kernel(const float4* __restrict__ x4, float* __restrict__ r) {
    int gtid = blockIdx.x * blockDim.x + threadIdx.x;
    int row = gtid >> 4, sub = gtid & 15;
    if (row >= N_NODES) return;
    float4 a = x4[row * 16 + sub];
    float v = fmaxf(fmaxf(fabsf(a.x), fabsf(a.y)), fmaxf(fabsf(a.z), fabsf(a.w)));
    #pragma unroll
    for (int o = 8; o > 0; o >>= 1) v = fmaxf(v, __shfl_xor(v, o, 64));
    if (sub == 0) r[row] = v;
}

// amax_msg = max over edges with unprotected src of r[src]
__global__ void amax_msg_kernel(const int* __restrict__ src, const void* mask,
                                const float* __restrict__ r, Scalars* sc) {
    unsigned int flag = sc->layout_flag;
    float v = 0.0f;
    for (int e = blockIdx.x * blockDim.x + threadIdx.x; e < N_EDGES;
         e += gridDim.x * blockDim.x) {
        int s = src[e];
        if (!get_mask(mask, flag, s)) v = fmaxf(v, r[s]);
    }
    block_atomic_max(v, &sc->amax_msg);
}

// Fused message-quant + segment_sum: 16 lanes per edge (float4 per lane).
__global__ void scatter_kernel(const float4* __restrict__ x4, const int* __restrict__ src,
                               const int* __restrict__ dst, const void* mask,
                               const Scalars* __restrict__ sc, float* __restrict__ aggr) {
    int gtid = blockIdx.x * blockDim.x + threadIdx.x;
    int e = gtid >> 4, sub = gtid & 15;
    if (e >= N_EDGES) return;
    unsigned int flag = sc->layout_flag;
    float scale = fmaxf(__uint_as_float(sc->amax_msg) / QMAX, 1e-8f);
    int s = src[e], d = dst[e];
    float4 v = x4[s * 16 + sub];
    if (!get_mask(mask, flag, s)) {
        v.x = dq(v.x, scale); v.y = dq(v.y, scale);
        v.z = dq(v.z, scale); v.w = dq(v.w, scale);
    }
    float* ap = &aggr[d * D_FEAT + sub * 4];
    atomicAdd(ap + 0, v.x); atomicAdd(ap + 1, v.y);
    atomicAdd(ap + 2, v.z); atomicAdd(ap + 3, v.w);
}

// amax1 = max |aggr| over unprotected rows (block-reduced, grid-stride, float4)
__global__ void amax1_kernel(const float4* __restrict__ aggr, const void* mask,
                             Scalars* sc) {
    unsigned int flag = sc->layout_flag;
    float v = 0.0f;
    const int total4 = N_NODES * (D_FEAT / 4);
    for (int i = blockIdx.x * blockDim.x + threadIdx.x; i < total4;
         i += gridDim.x * blockDim.x) {
        int row = i >> 4;
        if (get_mask(mask, flag, row)) continue;
        float4 a = aggr[i];
        v = fmaxf(v, fmaxf(fmaxf(fabsf(a.x), fabsf(a.y)),
                           fmaxf(fabsf(a.z), fabsf(a.w))));
    }
    block_atomic_max(v, &sc->amax1);
}

// out = protected ? aggr : dq(aggr, s1)
// (second _degree_quant is an exact identity: amax2 == amax1 -> s2 == s1,
//  and dq(dq(x,s),s) == dq(x,s) since integer codes re-round exactly.)
__global__ void final_kernel(float4* __restrict__ aggr, const void* mask,
                             const Scalars* __restrict__ sc) {
    unsigned int flag = sc->layout_flag;
    float s1 = fmaxf(__uint_as_float(sc->amax1) / QMAX, 1e-8f);
    const int total4 = N_NODES * (D_FEAT / 4);
    for (int i = blockIdx.x * blockDim.x + threadIdx.x; i < total4;
         i += gridDim.x * blockDim.x) {
        int row = i >> 4;
        if (get_mask(mask, flag, row)) continue;  // identity for protected rows
        float4 a = aggr[i];
        a.x = dq(a.x, s1); a.y = dq(a.y, s1);
        a.z = dq(a.z, s1); a.w = dq(a.w, s1);
        aggr[i] = a;
    }
}

extern "C" void kernel_launch(void* const* d_in, const int* in_sizes, int n_in,
                              void* d_out, int out_size, void* d_ws, size_t ws_size,
                              hipStream_t stream) {
    const float* x    = (const float*)d_in[0];
    const int*   ei   = (const int*)d_in[1];
    const void*  mask = d_in[2];
    const int* src = ei;
    const int* dst = ei + N_EDGES;
    float* out = (float*)d_out;

    Scalars* sc = (Scalars*)d_ws;
    float* r = (float*)((char*)d_ws + 256);

    hipMemsetAsync(d_ws, 0, 256, stream);
    hipMemsetAsync(d_out, 0, (size_t)out_size * sizeof(float), stream);

    detect_kernel<<<98, 256, 0, stream>>>((const unsigned int*)mask, sc);

    rowmax_kernel<<<N_NODES * 16 / 256, 256, 0, stream>>>((const float4*)x, r);

    amax_msg_kernel<<<1024, 256, 0, stream>>>(src, mask, r, sc);

    scatter_kernel<<<N_EDGES * 16 / 256, 256, 0, stream>>>(
        (const float4*)x, src, dst, mask, sc, out);

    amax1_kernel<<<1024, 256, 0, stream>>>((const float4*)out, mask, sc);

    final_kernel<<<2048, 256, 0, stream>>>((float4*)out, mask, sc);
}

// Round 3
// 222.689 us; speedup vs baseline: 6.7558x; 4.0852x over previous
//
#include <hip/hip_runtime.h>
#include <hip/hip_bf16.h>
#include <stdint.h>

#define N_NODES 100000
#define N_EDGES 1000000
#define D_FEAT  64
#define QMAX    127.0f
#define NB_SCAN 391   // ceil(N_NODES/256)

struct Scalars {
    unsigned int layout_flag;  // bit1: mask stored as f32, bit0: bytes, none: int32
    unsigned int amax_msg;
    unsigned int amax1;
    unsigned int pad;
};

__device__ __forceinline__ bool get_mask(const void* mp, unsigned int flag, int i) {
    if (flag & 2u) return ((const float*)mp)[i] != 0.0f;
    if (flag & 1u) return ((const unsigned char*)mp)[i] != 0;
    return ((const int*)mp)[i] != 0;
}

__device__ __forceinline__ float wave_max(float v) {
    #pragma unroll
    for (int o = 32; o > 0; o >>= 1) v = fmaxf(v, __shfl_xor(v, o, 64));
    return v;
}

__device__ __forceinline__ void block_atomic_max(float v, unsigned int* target) {
    __shared__ float sm[4];
    v = wave_max(v);
    if ((threadIdx.x & 63) == 0) sm[threadIdx.x >> 6] = v;
    __syncthreads();
    if (threadIdx.x == 0) {
        v = fmaxf(fmaxf(sm[0], sm[1]), fmaxf(sm[2], sm[3]));
        if (v > 0.0f) atomicMax(target, __float_as_uint(v));
    }
}

__device__ __forceinline__ float dq(float x, float scale) {
    float t = rintf(x / scale);                 // round half-to-even = jnp.round
    t = fminf(fmaxf(t, -QMAX - 1.0f), QMAX);    // clip to [-128, 127]
    return t * scale;
}

// Detect how the bool mask was uploaded (int32 / bytes / f32 words).
__global__ void detect_kernel(const unsigned int* mw, Scalars* sc) {
    unsigned int f = 0;
    for (int i = blockIdx.x * blockDim.x + threadIdx.x; i < N_NODES / 4;
         i += gridDim.x * blockDim.x) {
        unsigned int w = mw[i];
        if (w == 0x3F800000u) f |= 2u;
        else if (w & 0xFFFFFF00u) f |= 1u;
    }
    if (f) atomicOr(&sc->layout_flag, f);
}

// r[row] = max_j |x[row,j]|  — 16 lanes per row, float4 loads.
__global__ void rowmax_kernel(const float4* __restrict__ x4, float* __restrict__ r) {
    int gtid = blockIdx.x * blockDim.x + threadIdx.x;
    int row = gtid >> 4, sub = gtid & 15;
    if (row >= N_NODES) return;
    float4 a = x4[row * 16 + sub];
    float v = fmaxf(fmaxf(fabsf(a.x), fabsf(a.y)), fmaxf(fabsf(a.z), fabsf(a.w)));
    #pragma unroll
    for (int o = 8; o > 0; o >>= 1) v = fmaxf(v, __shfl_xor(v, o, 64));
    if (sub == 0) r[row] = v;
}

// amax_msg = max over edges with unprotected src of r[src]
__global__ void amax_msg_kernel(const int* __restrict__ src, const void* mask,
                                const float* __restrict__ r, Scalars* sc) {
    unsigned int flag = sc->layout_flag;
    float v = 0.0f;
    for (int e = blockIdx.x * blockDim.x + threadIdx.x; e < N_EDGES;
         e += gridDim.x * blockDim.x) {
        int s = src[e];
        if (!get_mask(mask, flag, s)) v = fmaxf(v, r[s]);
    }
    block_atomic_max(v, &sc->amax_msg);
}

__global__ void hist_kernel(const int* __restrict__ dst, int* __restrict__ count) {
    int e = blockIdx.x * blockDim.x + threadIdx.x;
    if (e < N_EDGES) atomicAdd(&count[dst[e]], 1);
}

// --- 3-pass exclusive scan over count[N_NODES] ---
__global__ void scan1_kernel(const int* __restrict__ count, int* __restrict__ bsum) {
    __shared__ int sm[256];
    int t = threadIdx.x;
    int i = blockIdx.x * 256 + t;
    sm[t] = (i < N_NODES) ? count[i] : 0;
    __syncthreads();
    for (int o = 128; o > 0; o >>= 1) {
        if (t < o) sm[t] += sm[t + o];
        __syncthreads();
    }
    if (t == 0) bsum[blockIdx.x] = sm[0];
}

__global__ void scan2_kernel(int* __restrict__ bsum) {
    __shared__ int sm[512];
    int t = threadIdx.x;
    int v = (t < NB_SCAN) ? bsum[t] : 0;
    sm[t] = v;
    __syncthreads();
    for (int o = 1; o < 512; o <<= 1) {
        int add = (t >= o) ? sm[t - o] : 0;
        __syncthreads();
        sm[t] += add;
        __syncthreads();
    }
    if (t < NB_SCAN) bsum[t] = sm[t] - v;  // exclusive
}

__global__ void scan3_kernel(const int* __restrict__ count, const int* __restrict__ bsum,
                             int* __restrict__ offsets, int* __restrict__ cur) {
    __shared__ int sm[256];
    int t = threadIdx.x;
    int i = blockIdx.x * 256 + t;
    int v = (i < N_NODES) ? count[i] : 0;
    sm[t] = v;
    __syncthreads();
    for (int o = 1; o < 256; o <<= 1) {
        int add = (t >= o) ? sm[t - o] : 0;
        __syncthreads();
        sm[t] += add;
        __syncthreads();
    }
    if (i < N_NODES) {
        int excl = bsum[blockIdx.x] + sm[t] - v;
        offsets[i] = excl;
        cur[i] = excl;
        if (i == N_NODES - 1) offsets[N_NODES] = excl + v;
    }
}

__global__ void reorder_kernel(const int* __restrict__ src, const int* __restrict__ dst,
                               int* __restrict__ cur, int* __restrict__ sorted_src) {
    int e = blockIdx.x * blockDim.x + threadIdx.x;
    if (e >= N_EDGES) return;
    int pos = atomicAdd(&cur[dst[e]], 1);
    sorted_src[pos] = src[e];
}

// One wave per node: gather sorted messages, quant, register-accumulate,
// single coalesced row store. Also emits per-block |row|max (unprotected).
__global__ void aggregate_kernel(const float4* __restrict__ x4,
                                 const int* __restrict__ sorted_src,
                                 const int* __restrict__ offsets,
                                 const void* mask,
                                 const Scalars* __restrict__ sc,
                                 float4* __restrict__ out4,
                                 float* __restrict__ pmax) {
    int w = threadIdx.x >> 6;              // wave in block: 0..3
    int node = blockIdx.x * 4 + w;
    int lane = threadIdx.x & 63;
    int grp = lane >> 4, sub = lane & 15;  // 4 edge slots x 16 float4 lanes
    unsigned int flag = sc->layout_flag;
    float scale = fmaxf(__uint_as_float(sc->amax_msg) / QMAX, 1e-8f);
    float4 acc = {0.f, 0.f, 0.f, 0.f};
    if (node < N_NODES) {
        int beg = offsets[node], end = offsets[node + 1];
        for (int e = beg + grp; e < end; e += 4) {
            int s = sorted_src[e];
            float4 a = x4[s * 16 + sub];
            if (!get_mask(mask, flag, s)) {
                a.x = dq(a.x, scale); a.y = dq(a.y, scale);
                a.z = dq(a.z, scale); a.w = dq(a.w, scale);
            }
            acc.x += a.x; acc.y += a.y; acc.z += a.z; acc.w += a.w;
        }
    }
    // sum the 4 edge groups; every lane ends with its sub-slice's total
    #pragma unroll
    for (int o = 16; o <= 32; o <<= 1) {
        acc.x += __shfl_xor(acc.x, o, 64);
        acc.y += __shfl_xor(acc.y, o, 64);
        acc.z += __shfl_xor(acc.z, o, 64);
        acc.w += __shfl_xor(acc.w, o, 64);
    }
    float v = 0.0f;
    if (node < N_NODES) {
        if (grp == 0) out4[node * 16 + sub] = acc;
        if (!get_mask(mask, flag, node))
            v = fmaxf(fmaxf(fabsf(acc.x), fabsf(acc.y)),
                      fmaxf(fabsf(acc.z), fabsf(acc.w)));
    }
    #pragma unroll
    for (int o = 1; o <= 8; o <<= 1) v = fmaxf(v, __shfl_xor(v, o, 64));
    __shared__ float smx[4];
    if (lane == 0) smx[w] = v;
    __syncthreads();
    if (threadIdx.x == 0)
        pmax[blockIdx.x] = fmaxf(fmaxf(smx[0], smx[1]), fmaxf(smx[2], smx[3]));
}

// single block: amax1 = max(pmax[0..n))
__global__ void amax1_reduce_kernel(const float* __restrict__ pmax, int n, Scalars* sc) {
    __shared__ float sm[16];
    float v = 0.0f;
    for (int i = threadIdx.x; i < n; i += 1024) v = fmaxf(v, pmax[i]);
    v = wave_max(v);
    if ((threadIdx.x & 63) == 0) sm[threadIdx.x >> 6] = v;
    __syncthreads();
    if (threadIdx.x == 0) {
        #pragma unroll
        for (int k = 1; k < 16; ++k) v = fmaxf(v, sm[k]);
        sc->amax1 = __float_as_uint(v);
    }
}

// out = protected ? aggr : dq(aggr, s1)
// (second _degree_quant is an exact identity: amax2 == amax1 -> s2 == s1,
//  and dq(dq(x,s),s) == dq(x,s) since integer codes re-round exactly.)
__global__ void final_kernel(float4* __restrict__ aggr, const void* mask,
                             const Scalars* __restrict__ sc) {
    unsigned int flag = sc->layout_flag;
    float s1 = fmaxf(__uint_as_float(sc->amax1) / QMAX, 1e-8f);
    const int total4 = N_NODES * (D_FEAT / 4);
    for (int i = blockIdx.x * blockDim.x + threadIdx.x; i < total4;
         i += gridDim.x * blockDim.x) {
        int row = i >> 4;
        if (get_mask(mask, flag, row)) continue;
        float4 a = aggr[i];
        a.x = dq(a.x, s1); a.y = dq(a.y, s1);
        a.z = dq(a.z, s1); a.w = dq(a.w, s1);
        aggr[i] = a;
    }
}

extern "C" void kernel_launch(void* const* d_in, const int* in_sizes, int n_in,
                              void* d_out, int out_size, void* d_ws, size_t ws_size,
                              hipStream_t stream) {
    const float* x    = (const float*)d_in[0];
    const int*   ei   = (const int*)d_in[1];
    const void*  mask = d_in[2];
    const int* src = ei;
    const int* dst = ei + N_EDGES;

    char* ws = (char*)d_ws;
    Scalars* sc      = (Scalars*)(ws + 0);
    float* r         = (float*)(ws + 256);          // 400000 B
    int*   count     = (int*)  (ws + 400384);       // 400000 B
    int*   offsets   = (int*)  (ws + 800512);       // 400004 B
    int*   cur       = (int*)  (ws + 1200640);      // 400000 B
    int*   bsum      = (int*)  (ws + 1600768);      // 1564 B
    float* pmax      = (float*)(ws + 1602560);      // 100000 B
    int*   sorted_src= (int*)  (ws + 1702656);      // 4000000 B  (end ~5.44 MB)

    hipMemsetAsync(sc, 0, 256, stream);
    hipMemsetAsync(count, 0, N_NODES * sizeof(int), stream);

    detect_kernel<<<98, 256, 0, stream>>>((const unsigned int*)mask, sc);
    rowmax_kernel<<<N_NODES * 16 / 256, 256, 0, stream>>>((const float4*)x, r);
    hist_kernel<<<(N_EDGES + 255) / 256, 256, 0, stream>>>(dst, count);
    amax_msg_kernel<<<1024, 256, 0, stream>>>(src, mask, r, sc);

    scan1_kernel<<<NB_SCAN, 256, 0, stream>>>(count, bsum);
    scan2_kernel<<<1, 512, 0, stream>>>(bsum);
    scan3_kernel<<<NB_SCAN, 256, 0, stream>>>(count, bsum, offsets, cur);

    reorder_kernel<<<(N_EDGES + 255) / 256, 256, 0, stream>>>(src, dst, cur, sorted_src);

    const int NAGG = (N_NODES + 3) / 4;  // 25000 blocks, 4 nodes each
    aggregate_kernel<<<NAGG, 256, 0, stream>>>(
        (const float4*)x, sorted_src, offsets, mask, sc, (float4*)d_out, pmax);

    amax1_reduce_kernel<<<1, 1024, 0, stream>>>(pmax, NAGG, sc);

    final_kernel<<<2048, 256, 0, stream>>>((float4*)d_out, mask, sc);
}

// Round 4
// 121.960 us; speedup vs baseline: 12.3355x; 1.8259x over previous
//
#include <hip/hip_runtime.h>
#include <hip/hip_bf16.h>
#include <stdint.h>

#define N_NODES 100000
#define N_EDGES 1000000
#define D_FEAT  64
#define QMAX    127.0f

#define BSHIFT      7                 // 128 nodes per bucket
#define NODES_PER_B 128
#define NBUCK       782               // ceil(100000/128)
#define BCAP        1664              // avg 1279 edges/bucket, +10 sigma headroom
#define A_EBLK      8192
#define A_THREADS   512
#define A_NBLK      ((N_EDGES + A_EBLK - 1) / A_EBLK)   // 123
#define B_THREADS   512

struct Scalars {
    unsigned int layout_flag;  // bit1: mask stored as f32, bit0: bytes, none: int32
    unsigned int amax_msg;
    unsigned int amax1;
    unsigned int pad;
};

__device__ __forceinline__ bool get_mask(const void* mp, unsigned int flag, int i) {
    if (flag & 2u) return ((const float*)mp)[i] != 0.0f;
    if (flag & 1u) return ((const unsigned char*)mp)[i] != 0;
    return ((const int*)mp)[i] != 0;
}

__device__ __forceinline__ float wave_max(float v) {
    #pragma unroll
    for (int o = 32; o > 0; o >>= 1) v = fmaxf(v, __shfl_xor(v, o, 64));
    return v;
}

__device__ __forceinline__ float dq(float x, float scale) {
    float t = rintf(x / scale);                 // round half-to-even = jnp.round
    t = fminf(fmaxf(t, -QMAX - 1.0f), QMAX);    // clip to [-128, 127]
    return t * scale;
}

// Detect how the bool mask was uploaded (int32 / bytes / f32 words).
__global__ void detect_kernel(const unsigned int* mw, Scalars* sc) {
    unsigned int f = 0;
    for (int i = blockIdx.x * blockDim.x + threadIdx.x; i < N_NODES / 4;
         i += gridDim.x * blockDim.x) {
        unsigned int w = mw[i];
        if (w == 0x3F800000u) f |= 2u;
        else if (w & 0xFFFFFF00u) f |= 1u;
    }
    if (f) atomicOr(&sc->layout_flag, f);
}

// r[row] = max_j |x[row,j]|  — 16 lanes per row, float4 loads.
__global__ void rowmax_kernel(const float4* __restrict__ x4, float* __restrict__ r) {
    int gtid = blockIdx.x * blockDim.x + threadIdx.x;
    int row = gtid >> 4, sub = gtid & 15;
    if (row >= N_NODES) return;
    float4 a = x4[row * 16 + sub];
    float v = fmaxf(fmaxf(fabsf(a.x), fabsf(a.y)), fmaxf(fabsf(a.z), fabsf(a.w)));
    #pragma unroll
    for (int o = 8; o > 0; o >>= 1) v = fmaxf(v, __shfl_xor(v, o, 64));
    if (sub == 0) r[row] = v;
}

// Bucket edges by dst>>7 into fixed-capacity regions (packed src|ldst<<20),
// with per-block LDS histogram + one global reservation per (block,bucket)
// for write locality. Fuses the amax_msg reduction (r[src] over unprotected).
__global__ void bucket_kernel(const int* __restrict__ src, const int* __restrict__ dst,
                              const void* maskp, const float* __restrict__ r,
                              Scalars* sc, int* __restrict__ gcur,
                              unsigned int* __restrict__ region) {
    __shared__ int hist[NBUCK];
    __shared__ float smx[A_THREADS / 64];
    int t = threadIdx.x;
    for (int i = t; i < NBUCK; i += A_THREADS) hist[i] = 0;
    __syncthreads();
    int beg = blockIdx.x * A_EBLK;
    int end = beg + A_EBLK; if (end > N_EDGES) end = N_EDGES;
    for (int e = beg + t; e < end; e += A_THREADS)
        atomicAdd(&hist[dst[e] >> BSHIFT], 1);
    __syncthreads();
    for (int i = t; i < NBUCK; i += A_THREADS) {
        int h = hist[i];
        hist[i] = h ? atomicAdd(&gcur[i], h) : 0;   // now a bucket-relative cursor
    }
    __syncthreads();
    unsigned int flag = sc->layout_flag;
    float vmax = 0.0f;
    for (int e = beg + t; e < end; e += A_THREADS) {
        int s = src[e], d = dst[e];
        int b = d >> BSHIFT;
        int pos = atomicAdd(&hist[b], 1);
        if (pos < BCAP)
            region[b * BCAP + pos] =
                (unsigned)s | ((unsigned)(d & (NODES_PER_B - 1)) << 20);
        if (!get_mask(maskp, flag, s)) vmax = fmaxf(vmax, r[s]);
    }
    vmax = wave_max(vmax);
    if ((t & 63) == 0) smx[t >> 6] = vmax;
    __syncthreads();
    if (t == 0) {
        float v = smx[0];
        #pragma unroll
        for (int k = 1; k < A_THREADS / 64; ++k) v = fmaxf(v, smx[k]);
        if (v > 0.0f) atomicMax(&sc->amax_msg, __float_as_uint(v));
    }
}

// One block per bucket: LDS counting-sort by local dst, then register-accumulate
// gather per node, coalesced row store, fused per-block amax1 (unprotected rows).
__global__ void aggregate_kernel(const float4* __restrict__ x4,
                                 const unsigned int* __restrict__ region,
                                 const int* __restrict__ gcur,
                                 const void* maskp,
                                 const Scalars* __restrict__ sc,
                                 float4* __restrict__ out4,
                                 float* __restrict__ pmax) {
    __shared__ unsigned int pk[BCAP];
    __shared__ int srt[BCAP];
    __shared__ int cnt0[NODES_PER_B];
    __shared__ int scn[NODES_PER_B];
    __shared__ int cur[NODES_PER_B];
    __shared__ float smx[B_THREADS / 64];
    int b = blockIdx.x;
    int t = threadIdx.x;
    int ne = gcur[b]; if (ne > BCAP) ne = BCAP;
    if (t < NODES_PER_B) cnt0[t] = 0;
    __syncthreads();
    for (int i = t; i < ne; i += B_THREADS) {
        unsigned int w = region[b * BCAP + i];
        pk[i] = w;
        atomicAdd(&cnt0[w >> 20], 1);
    }
    __syncthreads();
    if (t < NODES_PER_B) scn[t] = cnt0[t];
    __syncthreads();
    for (int o = 1; o < NODES_PER_B; o <<= 1) {   // inclusive Hillis-Steele scan
        int add = 0;
        if (t < NODES_PER_B && t >= o) add = scn[t - o];
        __syncthreads();
        if (t < NODES_PER_B) scn[t] += add;
        __syncthreads();
    }
    if (t < NODES_PER_B) cur[t] = scn[t] - cnt0[t];   // exclusive offset
    __syncthreads();
    for (int i = t; i < ne; i += B_THREADS) {         // counting-sort scatter
        unsigned int w = pk[i];
        int pos = atomicAdd(&cur[w >> 20], 1);
        srt[pos] = (int)(w & 0xFFFFFu);
    }
    __syncthreads();

    unsigned int flag = sc->layout_flag;
    float scale = fmaxf(__uint_as_float(sc->amax_msg) / QMAX, 1e-8f);
    int grp = t >> 4, sub = t & 15;   // 32 groups of 16 lanes
    float vmax = 0.0f;
    for (int n = grp; n < NODES_PER_B; n += 32) {
        int node = b * NODES_PER_B + n;
        if (node >= N_NODES) break;
        int e1 = scn[n], e0 = e1 - cnt0[n];
        float4 acc = {0.f, 0.f, 0.f, 0.f};
        for (int e = e0; e < e1; ++e) {
            int s = srt[e];                 // LDS broadcast across the 16 lanes
            float4 a = x4[s * 16 + sub];
            if (!get_mask(maskp, flag, s)) {
                a.x = dq(a.x, scale); a.y = dq(a.y, scale);
                a.z = dq(a.z, scale); a.w = dq(a.w, scale);
            }
            acc.x += a.x; acc.y += a.y; acc.z += a.z; acc.w += a.w;
        }
        out4[node * 16 + sub] = acc;
        if (!get_mask(maskp, flag, node))
            vmax = fmaxf(vmax, fmaxf(fmaxf(fabsf(acc.x), fabsf(acc.y)),
                                     fmaxf(fabsf(acc.z), fabsf(acc.w))));
    }
    vmax = wave_max(vmax);
    if ((t & 63) == 0) smx[t >> 6] = vmax;
    __syncthreads();
    if (t == 0) {
        float v = smx[0];
        #pragma unroll
        for (int k = 1; k < B_THREADS / 64; ++k) v = fmaxf(v, smx[k]);
        pmax[b] = v;
    }
}

// single block: amax1 = max(pmax[0..n))
__global__ void amax1_reduce_kernel(const float* __restrict__ pmax, int n, Scalars* sc) {
    __shared__ float sm[16];
    float v = 0.0f;
    for (int i = threadIdx.x; i < n; i += 1024) v = fmaxf(v, pmax[i]);
    v = wave_max(v);
    if ((threadIdx.x & 63) == 0) sm[threadIdx.x >> 6] = v;
    __syncthreads();
    if (threadIdx.x == 0) {
        #pragma unroll
        for (int k = 1; k < 16; ++k) v = fmaxf(v, sm[k]);
        sc->amax1 = __float_as_uint(v);
    }
}

// out = protected ? aggr : dq(aggr, s1)
// (second _degree_quant is an exact identity: amax2 == amax1 -> s2 == s1,
//  and dq(dq(x,s),s) == dq(x,s) since integer codes re-round exactly.)
__global__ void final_kernel(float4* __restrict__ aggr, const void* mask,
                             const Scalars* __restrict__ sc) {
    unsigned int flag = sc->layout_flag;
    float s1 = fmaxf(__uint_as_float(sc->amax1) / QMAX, 1e-8f);
    const int total4 = N_NODES * (D_FEAT / 4);
    for (int i = blockIdx.x * blockDim.x + threadIdx.x; i < total4;
         i += gridDim.x * blockDim.x) {
        int row = i >> 4;
        if (get_mask(mask, flag, row)) continue;
        float4 a = aggr[i];
        a.x = dq(a.x, s1); a.y = dq(a.y, s1);
        a.z = dq(a.z, s1); a.w = dq(a.w, s1);
        aggr[i] = a;
    }
}

extern "C" void kernel_launch(void* const* d_in, const int* in_sizes, int n_in,
                              void* d_out, int out_size, void* d_ws, size_t ws_size,
                              hipStream_t stream) {
    const float* x    = (const float*)d_in[0];
    const int*   ei   = (const int*)d_in[1];
    const void*  mask = d_in[2];
    const int* src = ei;
    const int* dst = ei + N_EDGES;

    char* ws = (char*)d_ws;
    Scalars* sc          = (Scalars*)(ws + 0);            // 256 B
    float* r             = (float*)  (ws + 256);          // 400000 B
    int*   gcur          = (int*)    (ws + 400256);       // 3128 B
    float* pmax          = (float*)  (ws + 403384);       // 3128 B
    unsigned int* region = (unsigned int*)(ws + 406528);  // 782*1664*4 = 5204992 B

    hipMemsetAsync(sc, 0, 256, stream);
    hipMemsetAsync(gcur, 0, NBUCK * sizeof(int), stream);

    detect_kernel<<<98, 256, 0, stream>>>((const unsigned int*)mask, sc);
    rowmax_kernel<<<N_NODES * 16 / 256, 256, 0, stream>>>((const float4*)x, r);

    bucket_kernel<<<A_NBLK, A_THREADS, 0, stream>>>(src, dst, mask, r, sc, gcur, region);

    aggregate_kernel<<<NBUCK, B_THREADS, 0, stream>>>(
        (const float4*)x, region, gcur, mask, sc, (float4*)d_out, pmax);

    amax1_reduce_kernel<<<1, 1024, 0, stream>>>(pmax, NBUCK, sc);

    final_kernel<<<2048, 256, 0, stream>>>((float4*)d_out, mask, sc);
}

// Round 5
// 109.885 us; speedup vs baseline: 13.6911x; 1.1099x over previous
//
#include <hip/hip_runtime.h>
#include <hip/hip_bf16.h>
#include <stdint.h>

#define N_NODES 100000
#define N_EDGES 1000000
#define D_FEAT  64
#define QMAX    127.0f

#define BSHIFT      7                 // 128 nodes per bucket
#define NODES_PER_B 128
#define NBUCK       782               // ceil(100000/128)
#define BCAP        1664              // avg 1279 edges/bucket, +10 sigma headroom
#define A_EBLK      8192
#define A_THREADS   512
#define A_NBLK      ((N_EDGES + A_EBLK - 1) / A_EBLK)   // 123
#define B_THREADS   512

struct Scalars {
    unsigned int layout_flag;  // bit1: mask stored as f32, bit0: bytes, none: int32
    unsigned int amax_msg;
    unsigned int amax1;
    unsigned int pad;
};

__device__ __forceinline__ bool get_mask(const void* mp, unsigned int flag, int i) {
    if (flag & 2u) return ((const float*)mp)[i] != 0.0f;
    if (flag & 1u) return ((const unsigned char*)mp)[i] != 0;
    return ((const int*)mp)[i] != 0;
}

__device__ __forceinline__ float wave_max(float v) {
    #pragma unroll
    for (int o = 32; o > 0; o >>= 1) v = fmaxf(v, __shfl_xor(v, o, 64));
    return v;
}

__device__ __forceinline__ float dq(float x, float scale) {
    float t = rintf(x / scale);                 // round half-to-even = jnp.round
    t = fminf(fmaxf(t, -QMAX - 1.0f), QMAX);    // clip to [-128, 127]
    return t * scale;
}

// Detect how the bool mask was uploaded (int32 / bytes / f32 words).
__global__ void detect_kernel(const unsigned int* mw, Scalars* sc) {
    unsigned int f = 0;
    for (int i = blockIdx.x * blockDim.x + threadIdx.x; i < N_NODES / 4;
         i += gridDim.x * blockDim.x) {
        unsigned int w = mw[i];
        if (w == 0x3F800000u) f |= 2u;
        else if (w & 0xFFFFFF00u) f |= 1u;
    }
    if (f) atomicOr(&sc->layout_flag, f);
}

// r[row] = max_j |x[row,j]|  — 16 lanes per row, float4 loads.
__global__ void rowmax_kernel(const float4* __restrict__ x4, float* __restrict__ r) {
    int gtid = blockIdx.x * blockDim.x + threadIdx.x;
    int row = gtid >> 4, sub = gtid & 15;
    if (row >= N_NODES) return;
    float4 a = x4[row * 16 + sub];
    float v = fmaxf(fmaxf(fabsf(a.x), fabsf(a.y)), fmaxf(fabsf(a.z), fabsf(a.w)));
    #pragma unroll
    for (int o = 8; o > 0; o >>= 1) v = fmaxf(v, __shfl_xor(v, o, 64));
    if (sub == 0) r[row] = v;
}

// Bucket edges by dst>>7 into fixed-capacity regions (packed src|ldst<<20),
// per-block LDS histogram + one global reservation per (block,bucket).
// Fuses the amax_msg reduction. dst chunk stashed in LDS to avoid re-read.
__global__ void bucket_kernel(const int* __restrict__ src, const int* __restrict__ dst,
                              const void* maskp, const float* __restrict__ r,
                              Scalars* sc, int* __restrict__ gcur,
                              unsigned int* __restrict__ region) {
    __shared__ int hist[NBUCK];
    __shared__ int dlds[A_EBLK];
    __shared__ float smx[A_THREADS / 64];
    int t = threadIdx.x;
    for (int i = t; i < NBUCK; i += A_THREADS) hist[i] = 0;
    __syncthreads();
    int beg = blockIdx.x * A_EBLK;
    int end = beg + A_EBLK; if (end > N_EDGES) end = N_EDGES;
    for (int e = beg + t; e < end; e += A_THREADS) {
        int d = dst[e];
        dlds[e - beg] = d;
        atomicAdd(&hist[d >> BSHIFT], 1);
    }
    __syncthreads();
    for (int i = t; i < NBUCK; i += A_THREADS) {
        int h = hist[i];
        hist[i] = h ? atomicAdd(&gcur[i], h) : 0;   // bucket-relative cursor
    }
    __syncthreads();
    unsigned int flag = sc->layout_flag;
    float vmax = 0.0f;
    for (int e = beg + t; e < end; e += A_THREADS) {
        int s = src[e], d = dlds[e - beg];
        int b = d >> BSHIFT;
        int pos = atomicAdd(&hist[b], 1);
        if (pos < BCAP)
            region[b * BCAP + pos] =
                (unsigned)s | ((unsigned)(d & (NODES_PER_B - 1)) << 20);
        if (!get_mask(maskp, flag, s)) vmax = fmaxf(vmax, r[s]);
    }
    vmax = wave_max(vmax);
    if ((t & 63) == 0) smx[t >> 6] = vmax;
    __syncthreads();
    if (t == 0) {
        float v = smx[0];
        #pragma unroll
        for (int k = 1; k < A_THREADS / 64; ++k) v = fmaxf(v, smx[k]);
        if (v > 0.0f) atomicMax(&sc->amax_msg, __float_as_uint(v));
    }
}

// msg[i] = mask[row] ? x[i] : dq(x[i], s_msg)   (dense per-node pass)
__global__ void msg_quant_kernel(const float4* __restrict__ x4, const void* maskp,
                                 const Scalars* __restrict__ sc,
                                 float4* __restrict__ msg4) {
    int i = blockIdx.x * blockDim.x + threadIdx.x;
    const int total4 = N_NODES * (D_FEAT / 4);
    if (i >= total4) return;
    unsigned int flag = sc->layout_flag;
    float scale = fmaxf(__uint_as_float(sc->amax_msg) / QMAX, 1e-8f);
    float4 a = x4[i];
    if (!get_mask(maskp, flag, i >> 4)) {
        a.x = dq(a.x, scale); a.y = dq(a.y, scale);
        a.z = dq(a.z, scale); a.w = dq(a.w, scale);
    }
    msg4[i] = a;
}

// ---- shared LDS-sort prologue for both aggregate variants ----
#define AGG_SORT_PROLOGUE                                                     \
    __shared__ unsigned int pk[BCAP];                                         \
    __shared__ int srt[BCAP];                                                 \
    __shared__ int cnt0[NODES_PER_B];                                         \
    __shared__ int scn[NODES_PER_B];                                          \
    __shared__ int cur[NODES_PER_B];                                          \
    __shared__ float smx[B_THREADS / 64];                                     \
    int b = blockIdx.x;                                                       \
    int t = threadIdx.x;                                                      \
    int ne = gcur[b]; if (ne > BCAP) ne = BCAP;                               \
    if (t < NODES_PER_B) cnt0[t] = 0;                                         \
    __syncthreads();                                                          \
    for (int i = t; i < ne; i += B_THREADS) {                                 \
        unsigned int w = region[b * BCAP + i];                                \
        pk[i] = w;                                                            \
        atomicAdd(&cnt0[w >> 20], 1);                                         \
    }                                                                         \
    __syncthreads();                                                          \
    if (t < NODES_PER_B) scn[t] = cnt0[t];                                    \
    __syncthreads();                                                          \
    for (int o = 1; o < NODES_PER_B; o <<= 1) {                               \
        int add = 0;                                                          \
        if (t < NODES_PER_B && t >= o) add = scn[t - o];                      \
        __syncthreads();                                                      \
        if (t < NODES_PER_B) scn[t] += add;                                   \
        __syncthreads();                                                      \
    }                                                                         \
    if (t < NODES_PER_B) cur[t] = scn[t] - cnt0[t];                           \
    __syncthreads();                                                          \
    for (int i = t; i < ne; i += B_THREADS) {                                 \
        unsigned int w = pk[i];                                               \
        int pos = atomicAdd(&cur[w >> 20], 1);                                \
        srt[pos] = (int)(w & 0xFFFFFu);                                       \
    }                                                                         \
    __syncthreads();

#define AGG_EPILOGUE                                                          \
    vmax = wave_max(vmax);                                                    \
    if ((t & 63) == 0) smx[t >> 6] = vmax;                                    \
    __syncthreads();                                                          \
    if (t == 0) {                                                             \
        float v = smx[0];                                                     \
        _Pragma("unroll")                                                     \
        for (int k = 1; k < B_THREADS / 64; ++k) v = fmaxf(v, smx[k]);        \
        pmax[b] = v;                                                          \
    }

// FAST: pure gather-sum of precomputed msg rows. No per-edge mask/dq.
__global__ void aggregate_fast_kernel(const float4* __restrict__ msg4,
                                      const unsigned int* __restrict__ region,
                                      const int* __restrict__ gcur,
                                      const void* maskp,
                                      const Scalars* __restrict__ sc,
                                      float4* __restrict__ out4,
                                      float* __restrict__ pmax) {
    AGG_SORT_PROLOGUE
    unsigned int flag = sc->layout_flag;
    int grp = t >> 4, sub = t & 15;   // 32 groups of 16 lanes
    float vmax = 0.0f;
    for (int n = grp; n < NODES_PER_B; n += 32) {
        int node = b * NODES_PER_B + n;
        if (node >= N_NODES) break;
        int e1 = scn[n], e0 = e1 - cnt0[n];
        float4 acc = {0.f, 0.f, 0.f, 0.f};
        int e = e0;
        for (; e + 1 < e1; e += 2) {           // 2 gathers in flight
            int s0 = srt[e], s1 = srt[e + 1];
            float4 a0 = msg4[s0 * 16 + sub];
            float4 a1 = msg4[s1 * 16 + sub];
            acc.x += a0.x; acc.y += a0.y; acc.z += a0.z; acc.w += a0.w;
            acc.x += a1.x; acc.y += a1.y; acc.z += a1.z; acc.w += a1.w;
        }
        if (e < e1) {
            float4 a = msg4[srt[e] * 16 + sub];
            acc.x += a.x; acc.y += a.y; acc.z += a.z; acc.w += a.w;
        }
        out4[node * 16 + sub] = acc;
        if (!get_mask(maskp, flag, node))
            vmax = fmaxf(vmax, fmaxf(fmaxf(fabsf(acc.x), fabsf(acc.y)),
                                     fmaxf(fabsf(acc.z), fabsf(acc.w))));
    }
    AGG_EPILOGUE
}

// FALLBACK (small ws): per-edge quant fused in gather (R4 behavior).
__global__ void aggregate_q_kernel(const float4* __restrict__ x4,
                                   const unsigned int* __restrict__ region,
                                   const int* __restrict__ gcur,
                                   const void* maskp,
                                   const Scalars* __restrict__ sc,
                                   float4* __restrict__ out4,
                                   float* __restrict__ pmax) {
    AGG_SORT_PROLOGUE
    unsigned int flag = sc->layout_flag;
    float scale = fmaxf(__uint_as_float(sc->amax_msg) / QMAX, 1e-8f);
    int grp = t >> 4, sub = t & 15;
    float vmax = 0.0f;
    for (int n = grp; n < NODES_PER_B; n += 32) {
        int node = b * NODES_PER_B + n;
        if (node >= N_NODES) break;
        int e1 = scn[n], e0 = e1 - cnt0[n];
        float4 acc = {0.f, 0.f, 0.f, 0.f};
        for (int e = e0; e < e1; ++e) {
            int s = srt[e];
            float4 a = x4[s * 16 + sub];
            if (!get_mask(maskp, flag, s)) {
                a.x = dq(a.x, scale); a.y = dq(a.y, scale);
                a.z = dq(a.z, scale); a.w = dq(a.w, scale);
            }
            acc.x += a.x; acc.y += a.y; acc.z += a.z; acc.w += a.w;
        }
        out4[node * 16 + sub] = acc;
        if (!get_mask(maskp, flag, node))
            vmax = fmaxf(vmax, fmaxf(fmaxf(fabsf(acc.x), fabsf(acc.y)),
                                     fmaxf(fabsf(acc.z), fabsf(acc.w))));
    }
    AGG_EPILOGUE
}

// single block: amax1 = max(pmax[0..n))
__global__ void amax1_reduce_kernel(const float* __restrict__ pmax, int n, Scalars* sc) {
    __shared__ float sm[16];
    float v = 0.0f;
    for (int i = threadIdx.x; i < n; i += 1024) v = fmaxf(v, pmax[i]);
    v = wave_max(v);
    if ((threadIdx.x & 63) == 0) sm[threadIdx.x >> 6] = v;
    __syncthreads();
    if (threadIdx.x == 0) {
        #pragma unroll
        for (int k = 1; k < 16; ++k) v = fmaxf(v, sm[k]);
        sc->amax1 = __float_as_uint(v);
    }
}

// out = protected ? aggr : dq(aggr, s1)
// (second _degree_quant is an exact identity: amax2 == amax1 -> s2 == s1,
//  and dq(dq(x,s),s) == dq(x,s) since integer codes re-round exactly.)
__global__ void final_kernel(float4* __restrict__ aggr, const void* mask,
                             const Scalars* __restrict__ sc) {
    unsigned int flag = sc->layout_flag;
    float s1 = fmaxf(__uint_as_float(sc->amax1) / QMAX, 1e-8f);
    const int total4 = N_NODES * (D_FEAT / 4);
    for (int i = blockIdx.x * blockDim.x + threadIdx.x; i < total4;
         i += gridDim.x * blockDim.x) {
        int row = i >> 4;
        if (get_mask(mask, flag, row)) continue;
        float4 a = aggr[i];
        a.x = dq(a.x, s1); a.y = dq(a.y, s1);
        a.z = dq(a.z, s1); a.w = dq(a.w, s1);
        aggr[i] = a;
    }
}

extern "C" void kernel_launch(void* const* d_in, const int* in_sizes, int n_in,
                              void* d_out, int out_size, void* d_ws, size_t ws_size,
                              hipStream_t stream) {
    const float* x    = (const float*)d_in[0];
    const int*   ei   = (const int*)d_in[1];
    const void*  mask = d_in[2];
    const int* src = ei;
    const int* dst = ei + N_EDGES;

    char* ws = (char*)d_ws;
    Scalars* sc   = (Scalars*)(ws + 0);            // 256 B
    float* r      = (float*)  (ws + 256);          // 400000 B
    int*   gcur   = (int*)    (ws + 400256);       // 3128 B
    float* pmax   = (float*)  (ws + 403384);       // 3128 B
    float* msg    = (float*)  (ws + 406528);       // 25600000 B
    const size_t REGION_FAST = 406528 + 25600000;  // 26006528
    const size_t REGION_BYTES = (size_t)NBUCK * BCAP * 4;
    bool fast = ws_size >= REGION_FAST + REGION_BYTES;        // ~31.2 MB
    unsigned int* region = (unsigned int*)(ws + (fast ? REGION_FAST : 406528));

    hipMemsetAsync(sc, 0, 256, stream);
    hipMemsetAsync(gcur, 0, NBUCK * sizeof(int), stream);

    detect_kernel<<<98, 256, 0, stream>>>((const unsigned int*)mask, sc);
    rowmax_kernel<<<N_NODES * 16 / 256, 256, 0, stream>>>((const float4*)x, r);

    bucket_kernel<<<A_NBLK, A_THREADS, 0, stream>>>(src, dst, mask, r, sc, gcur, region);

    const int total4 = N_NODES * (D_FEAT / 4);
    if (fast) {
        msg_quant_kernel<<<(total4 + 255) / 256, 256, 0, stream>>>(
            (const float4*)x, mask, sc, (float4*)msg);
        aggregate_fast_kernel<<<NBUCK, B_THREADS, 0, stream>>>(
            (const float4*)msg, region, gcur, mask, sc, (float4*)d_out, pmax);
    } else {
        aggregate_q_kernel<<<NBUCK, B_THREADS, 0, stream>>>(
            (const float4*)x, region, gcur, mask, sc, (float4*)d_out, pmax);
    }

    amax1_reduce_kernel<<<1, 1024, 0, stream>>>(pmax, NBUCK, sc);

    final_kernel<<<2048, 256, 0, stream>>>((float4*)d_out, mask, sc);
}